// Round 6
// baseline (3557.971 us; speedup 1.0000x reference)
//
#include <hip/hip_runtime.h>
#include <hip/hip_bf16.h>
#include <stdint.h>

#define HID 1024

// ---------------- threefry2x32, key = (0,1) (jax.random.key(1)) ----------------
__device__ __forceinline__ uint32_t rotl32(uint32_t x, int r) {
  return (x << r) | (x >> (32 - r));
}

__device__ __forceinline__ uint2 threefry2x32_01(uint32_t x0, uint32_t x1) {
  const uint32_t k0 = 0u, k1 = 1u;
  const uint32_t k2 = k0 ^ k1 ^ 0x1BD11BDAu;
  x0 += k0; x1 += k1;
#define TF_R(r) { x0 += x1; x1 = rotl32(x1, r); x1 ^= x0; }
  TF_R(13) TF_R(15) TF_R(26) TF_R(6)
  x0 += k1; x1 += k2 + 1u;
  TF_R(17) TF_R(29) TF_R(16) TF_R(24)
  x0 += k2; x1 += k0 + 2u;
  TF_R(13) TF_R(15) TF_R(26) TF_R(6)
  x0 += k0; x1 += k1 + 3u;
  TF_R(17) TF_R(29) TF_R(16) TF_R(24)
  x0 += k1; x1 += k2 + 4u;
  TF_R(13) TF_R(15) TF_R(26) TF_R(6)
  x0 += k2; x1 += k0 + 5u;
#undef TF_R
  return make_uint2(x0, x1);
}

// uniform-in-[0,1) bits -> u, jax partitionable mode: ctr=(0, idx), bits = out0^out1
__device__ __forceinline__ float uni_at(uint32_t flat) {
  uint2 y = threefry2x32_01(0u, flat);
  uint32_t b = y.x ^ y.y;
  float f = __uint_as_float((b >> 9) | 0x3f800000u) - 1.0f;
  return fmaxf(f, 1.17549435e-38f);
}

// FAST gumbel: v_log_f32-based, |err| <~ 3e-5 absolute. Hot path (67M calls).
__device__ __forceinline__ float gumbel_fast(uint32_t flat) {
  float u = uni_at(flat);
  float w = -__logf(u);
  return -__logf(w);
}

// EXACT gumbel: correctly-rounded f32 log via double. Called ~2x per row-partial.
__device__ __noinline__ float gumbel_exact(uint32_t flat) {
  float u = uni_at(flat);
  float w = -(float)log((double)u);
  float o = (float)log((double)w);
  return -o;
}

__device__ __forceinline__ float f4c(const float4& v, int i) {
  return i == 0 ? v.x : (i == 1 ? v.y : (i == 2 ? v.z : v.w));
}

// rank predicate: (av,ai) strictly above (bv,bi) under first-index-argmax order
__device__ __forceinline__ bool rank_above(float av, int ai, float bv, int bi) {
  return av > bv || (av == bv && ai < bi);
}

// ---------------- generic tiled fp32 GEMM: C = act(A) @ B + bias ----------------
// act(x) = FUSE_BN ? relu(bna[k]*x + bnc[k]) : x   (per-k column params)
template<int BM, int BN_, int BK, int TM, int TN, bool FUSE_BN>
__global__ void __launch_bounds__(256, 4) gemm_bn_relu(
    const float* __restrict__ A, const float* __restrict__ B,
    const float* __restrict__ bias, const float* __restrict__ bna,
    const float* __restrict__ bnc, float* __restrict__ C,
    int M, int N, int K)
{
  __shared__ __align__(16) float As[BK][BM + 4];
  __shared__ __align__(16) float Bs[BK][BN_];
  const int t = threadIdx.x;
  const int n0 = blockIdx.x * BN_;
  const int m0 = blockIdx.y * BM;
  const int tn = t % (BN_ / TN);
  const int tm = t / (BN_ / TN);

  float acc[TM][TN];
#pragma unroll
  for (int i = 0; i < TM; ++i)
#pragma unroll
    for (int j = 0; j < TN; ++j) acc[i][j] = 0.f;

  for (int k0 = 0; k0 < K; k0 += BK) {
    __syncthreads();
    // stage A (BN+ReLU fused), transposed to [k][m]
#pragma unroll
    for (int p = 0; p < BM * BK / 1024; ++p) {
      int f = t + p * 256;
      int kq = f % (BK / 4);
      int m = f / (BK / 4);
      float4 v = *(const float4*)(A + (size_t)(m0 + m) * K + (k0 + kq * 4));
      if constexpr (FUSE_BN) {
        float4 a4 = *(const float4*)(bna + k0 + kq * 4);
        float4 c4 = *(const float4*)(bnc + k0 + kq * 4);
        v.x = fmaxf(fmaf(v.x, a4.x, c4.x), 0.f);
        v.y = fmaxf(fmaf(v.y, a4.y, c4.y), 0.f);
        v.z = fmaxf(fmaf(v.z, a4.z, c4.z), 0.f);
        v.w = fmaxf(fmaf(v.w, a4.w, c4.w), 0.f);
      }
      As[kq * 4 + 0][m] = v.x;
      As[kq * 4 + 1][m] = v.y;
      As[kq * 4 + 2][m] = v.z;
      As[kq * 4 + 3][m] = v.w;
    }
    // stage B
#pragma unroll
    for (int p = 0; p < BK * BN_ / 1024; ++p) {
      int f = t + p * 256;
      int n4 = f % (BN_ / 4);
      int k = f / (BN_ / 4);
      *(float4*)&Bs[k][n4 * 4] =
          *(const float4*)(B + (size_t)(k0 + k) * N + (n0 + n4 * 4));
    }
    __syncthreads();
#pragma unroll 4
    for (int kk = 0; kk < BK; ++kk) {
      float a[TM], b[TN];
      {
        float4 q0 = *(const float4*)&As[kk][tm * 4];
        a[0] = q0.x; a[1] = q0.y; a[2] = q0.z; a[3] = q0.w;
        if constexpr (TM == 8) {
          float4 q1 = *(const float4*)&As[kk][tm * 4 + BM / 2];
          a[4] = q1.x; a[5] = q1.y; a[6] = q1.z; a[7] = q1.w;
        }
        float4 r0 = *(const float4*)&Bs[kk][tn * 4];
        b[0] = r0.x; b[1] = r0.y; b[2] = r0.z; b[3] = r0.w;
        if constexpr (TN == 8) {
          float4 r1 = *(const float4*)&Bs[kk][tn * 4 + BN_ / 2];
          b[4] = r1.x; b[5] = r1.y; b[6] = r1.z; b[7] = r1.w;
        }
      }
#pragma unroll
      for (int i = 0; i < TM; ++i)
#pragma unroll
        for (int j = 0; j < TN; ++j)
          acc[i][j] = fmaf(a[i], b[j], acc[i][j]);
    }
  }
  // epilogue
#pragma unroll
  for (int i = 0; i < TM; ++i) {
    int m = (i < 4) ? (tm * 4 + i) : (tm * 4 + BM / 2 + (i - 4));
#pragma unroll
    for (int jq = 0; jq < TN / 4; ++jq) {
      int n = tn * 4 + jq * (BN_ / 2);
      float4 bv = *(const float4*)(bias + n0 + n);
      float4 o;
      o.x = acc[i][jq * 4 + 0] + bv.x;
      o.y = acc[i][jq * 4 + 1] + bv.y;
      o.z = acc[i][jq * 4 + 2] + bv.z;
      o.w = acc[i][jq * 4 + 3] + bv.w;
      *(float4*)(C + (size_t)(m0 + m) * N + (n0 + n)) = o;
    }
  }
}

// ---------------- codebook bits input layer: X[k][h] = b_in[h] + sum_j bit(k,j)*w_in[j][h]
__global__ void __launch_bounds__(256) embed_bits_in(
    const float* __restrict__ w_in, const float* __restrict__ b_in,
    float* __restrict__ X)
{
  int k = blockIdx.x;
  int c = threadIdx.x * 4;
  float4 acc = *(const float4*)(b_in + c);
#pragma unroll
  for (int j = 0; j < 13; ++j) {
    if (k & (1 << (12 - j))) {
      float4 w = *(const float4*)(w_in + j * HID + c);
      acc.x += w.x; acc.y += w.y; acc.z += w.z; acc.w += w.w;
    }
  }
  *(float4*)(X + (size_t)k * HID + c) = acc;
}

// ---------------- BN stats, stage A: per (rowblock, col) partial sum/sumsq ----------------
__global__ void __launch_bounds__(256) bn_stats_partial(
    const float* __restrict__ X, float* __restrict__ part)
{
  int cb = blockIdx.x, rb = blockIdx.y;
  int t = threadIdx.x;
  int cl = t & 31, rs = t >> 5;
  int c = cb * 32 + cl;
  int r0 = rb * 256 + rs * 32;
  float s = 0.f, sq = 0.f;
  const float* p = X + (size_t)r0 * HID + c;
  for (int i = 0; i < 32; ++i) {
    float v = p[(size_t)i * HID];
    s += v;
    sq = fmaf(v, v, sq);
  }
  __shared__ float rs_[8][32], rq_[8][32];
  rs_[rs][cl] = s;
  rq_[rs][cl] = sq;
  __syncthreads();
  if (t < 32) {
    float S = 0.f, Q = 0.f;
    for (int i = 0; i < 8; ++i) { S += rs_[i][t]; Q += rq_[i][t]; }
    size_t o = ((size_t)rb * HID + cb * 32 + t) * 2;
    part[o] = S;
    part[o + 1] = Q;
  }
}

// ---------------- BN stats, stage B: finalize a[k] = g*rsqrt(var+eps), c[k] = b - m*a ----------------
__global__ void __launch_bounds__(256) bn_finalize(
    const float* __restrict__ part, const float* __restrict__ gamma,
    const float* __restrict__ beta, float* __restrict__ bna,
    float* __restrict__ bnc)
{
  int c = blockIdx.x * 256 + threadIdx.x;
  double S = 0.0, Q = 0.0;
  for (int rb = 0; rb < 32; ++rb) {
    size_t o = ((size_t)rb * HID + c) * 2;
    S += (double)part[o];
    Q += (double)part[o + 1];
  }
  double mean = S / 8192.0;
  double var = Q / 8192.0 - mean * mean;
  float r = (float)(1.0 / sqrt(var + 1e-5));
  float a = gamma[c] * r;
  bna[c] = a;
  bnc[c] = fmaf(-(float)mean, a, beta[c]);
}

// ---------------- row normalize (64-wide rows): out = x / (||x|| + 1e-6) ----------------
__global__ void __launch_bounds__(64) row_normalize64(
    const float* __restrict__ in, float* __restrict__ out)
{
  int r = blockIdx.x, t = threadIdx.x;
  float v = in[(size_t)r * 64 + t];
  float ss = v * v;
  for (int m = 32; m >= 1; m >>= 1) ss += __shfl_xor(ss, m);
  float inv = 1.f / (sqrtf(ss) + 1e-6f);
  out[(size_t)r * 64 + t] = v * inv;
}

// ---------------- score kernel v2: LDS-balanced (R=8 rows/thread, Q=16 ks/lane) ----
// grid = 512: (bid>>2) = 64-row block, (bid&3) = k-quarter (2048 cols).
// Per block: 4 k-tiles of 512; Ed staged per 16-d chunk as Ed[d][k].
// d-accumulation order is 0..63 sequential -> dots bit-identical to prior rounds.
// GUM=true : z = 2*dot + gumbel; per-thread top-2 + cross-lane top-2 merge +
//            exact-gumbel fallback within 1e-3 margin (code-exact).
// GUM=false: z = dot (diag -> -1), rowmax for vq_loss.
template<bool GUM>
__global__ void __launch_bounds__(256, 2) score_kernel(
    const float* __restrict__ Arows, const float* __restrict__ eN,
    float* __restrict__ pval, int* __restrict__ pidx)
{
  __shared__ __align__(16) float Ed[16][516];
  __shared__ __align__(16) float Hs[64][68];
  const int t = threadIdx.x;
  const int rb = blockIdx.x >> 2;
  const int kq = blockIdx.x & 3;
  const int i0 = rb * 64;
  const int g = t >> 5;       // 8 row-groups
  const int lane = t & 31;
  const int r0 = g * 8;       // local row base (8 rows per thread)

  // stage Hs once (rows fixed for whole block)
#pragma unroll
  for (int p = 0; p < 4; ++p) {
    int f = t + p * 256;
    int row = f >> 4, ch = (f & 15) * 4;
    *(float4*)&Hs[row][ch] = *(const float4*)(Arows + (size_t)(i0 + row) * 64 + ch);
  }

  float b1[8], b2[8];
  int i1[8], i2[8];
#pragma unroll
  for (int r = 0; r < 8; ++r) { b1[r] = -3.4e38f; b2[r] = -3.4e38f; i1[r] = 0; i2[r] = 0; }

  for (int tile = 0; tile < 4; ++tile) {
    const int kb = kq * 2048 + tile * 512;
    float acc[8][16];
#pragma unroll
    for (int r = 0; r < 8; ++r)
#pragma unroll
      for (int q = 0; q < 16; ++q) acc[r][q] = 0.f;

    for (int dc = 0; dc < 4; ++dc) {
      __syncthreads();
      // stage Ed[d][k] = eN[kb+k][dc*16+d] for d in [0,16)
      {
        const int kk0 = t >> 2, d4 = (t & 3) * 4;
#pragma unroll
        for (int p = 0; p < 8; ++p) {
          int kk = kk0 + p * 64;
          float4 v = *(const float4*)(eN + (size_t)(kb + kk) * 64 + dc * 16 + d4);
          Ed[d4 + 0][kk] = v.x;
          Ed[d4 + 1][kk] = v.y;
          Ed[d4 + 2][kk] = v.z;
          Ed[d4 + 3][kk] = v.w;
        }
      }
      __syncthreads();
#pragma unroll
      for (int dq = 0; dq < 4; ++dq) {
        float4 hq[8];
#pragma unroll
        for (int r = 0; r < 8; ++r)
          hq[r] = *(const float4*)&Hs[r0 + r][dc * 16 + dq * 4];
#pragma unroll
        for (int dd = 0; dd < 4; ++dd) {
          const int d = dq * 4 + dd;
          float4 ev0 = *(const float4*)&Ed[d][0 * 128 + lane * 4];
          float4 ev1 = *(const float4*)&Ed[d][1 * 128 + lane * 4];
          float4 ev2 = *(const float4*)&Ed[d][2 * 128 + lane * 4];
          float4 ev3 = *(const float4*)&Ed[d][3 * 128 + lane * 4];
#pragma unroll
          for (int r = 0; r < 8; ++r) {
            const float h = f4c(hq[r], dd);
            acc[r][0]  = fmaf(h, ev0.x, acc[r][0]);
            acc[r][1]  = fmaf(h, ev0.y, acc[r][1]);
            acc[r][2]  = fmaf(h, ev0.z, acc[r][2]);
            acc[r][3]  = fmaf(h, ev0.w, acc[r][3]);
            acc[r][4]  = fmaf(h, ev1.x, acc[r][4]);
            acc[r][5]  = fmaf(h, ev1.y, acc[r][5]);
            acc[r][6]  = fmaf(h, ev1.z, acc[r][6]);
            acc[r][7]  = fmaf(h, ev1.w, acc[r][7]);
            acc[r][8]  = fmaf(h, ev2.x, acc[r][8]);
            acc[r][9]  = fmaf(h, ev2.y, acc[r][9]);
            acc[r][10] = fmaf(h, ev2.z, acc[r][10]);
            acc[r][11] = fmaf(h, ev2.w, acc[r][11]);
            acc[r][12] = fmaf(h, ev3.x, acc[r][12]);
            acc[r][13] = fmaf(h, ev3.y, acc[r][13]);
            acc[r][14] = fmaf(h, ev3.z, acc[r][14]);
            acc[r][15] = fmaf(h, ev3.w, acc[r][15]);
          }
        }
      }
    }
    // epilogue for this 512-k tile (ks ascending within thread)
#pragma unroll
    for (int r = 0; r < 8; ++r) {
      const int grow = i0 + r0 + r;
#pragma unroll
      for (int j = 0; j < 4; ++j) {
#pragma unroll
        for (int e = 0; e < 4; ++e) {
          const int kgl = kb + j * 128 + lane * 4 + e;
          if constexpr (GUM) {
            float gb = gumbel_fast(((uint32_t)grow << 13) | (uint32_t)kgl);
            float z = fmaf(2.f, acc[r][j * 4 + e], gb);
            if (z > b1[r]) {
              b2[r] = b1[r]; i2[r] = i1[r];
              b1[r] = z; i1[r] = kgl;
            } else if (z > b2[r]) {
              b2[r] = z; i2[r] = kgl;
            }
          } else {
            float z = (kgl == grow) ? -1.0f : acc[r][j * 4 + e];
            if (z > b1[r]) b1[r] = z;
          }
        }
      }
    }
  }
  // cross-lane (32 lanes per row-group) reduce + write partials
#pragma unroll
  for (int r = 0; r < 8; ++r) {
    if constexpr (GUM) {
      float v1 = b1[r], v2 = b2[r];
      int j1 = i1[r], j2 = i2[r];
      for (int m = 16; m >= 1; m >>= 1) {
        float o1 = __shfl_xor(v1, m), o2 = __shfl_xor(v2, m);
        int p1 = __shfl_xor(j1, m), p2 = __shfl_xor(j2, m);
        if (rank_above(o1, p1, v1, j1)) {
          float nv2; int nj2;
          if (rank_above(v1, j1, o2, p2)) { nv2 = v1; nj2 = j1; }
          else { nv2 = o2; nj2 = p2; }
          v1 = o1; j1 = p1; v2 = nv2; j2 = nj2;
        } else {
          if (rank_above(o1, p1, v2, j2)) { v2 = o1; j2 = p1; }
        }
      }
      if (lane == 0) {
        const uint32_t grow = (uint32_t)(i0 + r0 + r);
        float g1f = gumbel_fast((grow << 13) | (uint32_t)j1);
        float g1e = gumbel_exact((grow << 13) | (uint32_t)j1);
        float z1 = v1 - g1f + g1e;
        int win = j1;
        if (v1 - v2 <= 1e-3f) {
          float g2f = gumbel_fast((grow << 13) | (uint32_t)j2);
          float g2e = gumbel_exact((grow << 13) | (uint32_t)j2);
          float z2 = v2 - g2f + g2e;
          if (rank_above(z2, j2, z1, win)) { z1 = z2; win = j2; }
        }
        pval[(size_t)grow * 4 + kq] = z1;
        pidx[(size_t)grow * 4 + kq] = win;
      }
    } else {
      float bv = b1[r];
      for (int m = 16; m >= 1; m >>= 1) {
        float ov = __shfl_xor(bv, m);
        if (ov > bv) bv = ov;
      }
      if (lane == 0) {
        int grow = i0 + r0 + r;
        pval[(size_t)grow * 4 + kq] = bv;
      }
    }
  }
}

// ---------------- combine: codes, masked code output, per-block loss partial ----------------
__global__ void __launch_bounds__(256) combine_kernel(
    const float* __restrict__ pval, const int* __restrict__ pidx,
    const float* __restrict__ pmax, const int* __restrict__ mask,
    int* __restrict__ codes, float* __restrict__ out_code,
    float* __restrict__ losspart)
{
  int r = blockIdx.x * 256 + threadIdx.x;
  float bv = pval[(size_t)r * 4];
  int bi = pidx[(size_t)r * 4];
#pragma unroll
  for (int p = 1; p < 4; ++p) {
    float v = pval[(size_t)r * 4 + p];
    int i = pidx[(size_t)r * 4 + p];
    if (rank_above(v, i, bv, bi)) { bv = v; bi = i; }
  }
  codes[r] = bi;
  out_code[r] = (mask[r] != 0) ? (float)bi : 0.f;
  float m = fmaxf(fmaxf(pmax[(size_t)r * 4], pmax[(size_t)r * 4 + 1]),
                  fmaxf(pmax[(size_t)r * 4 + 2], pmax[(size_t)r * 4 + 3]));
  __shared__ float red[256];
  red[threadIdx.x] = m;
  __syncthreads();
  for (int s = 128; s >= 1; s >>= 1) {
    if (threadIdx.x < s) red[threadIdx.x] += red[threadIdx.x + s];
    __syncthreads();
  }
  if (threadIdx.x == 0) losspart[blockIdx.x] = red[0];
}

__global__ void __launch_bounds__(64) loss_final(
    const float* __restrict__ losspart, float* __restrict__ out)
{
  float s = (threadIdx.x < 32) ? losspart[threadIdx.x] : 0.f;
  for (int m = 32; m >= 1; m >>= 1) s += __shfl_xor(s, m);
  if (threadIdx.x == 0) out[0] = s * (1.0f / 8192.0f);
}

// ---------------- final projection: out = (mask ? eN[code] : 0) @ inv_w + inv_b ----------------
__global__ void __launch_bounds__(256, 2) final_proj(
    const float* __restrict__ eN, const int* __restrict__ codes,
    const int* __restrict__ mask, const float* __restrict__ inv_w,
    const float* __restrict__ inv_b, float* __restrict__ out)
{
  __shared__ __align__(16) float Ws[64][128];
  __shared__ __align__(16) float Es[32][64];
  const int t = threadIdx.x;
  const int c0 = blockIdx.x * 128;
  const int r0 = blockIdx.y * 32;
  for (int f = t; f < 512; f += 256) {
    int lr = f >> 4, dq = (f & 15) << 2;
    int grow = r0 + lr;
    float4 v = make_float4(0.f, 0.f, 0.f, 0.f);
    if (mask[grow] != 0)
      v = *(const float4*)(eN + (size_t)codes[grow] * 64 + dq);
    *(float4*)&Es[lr][dq] = v;
  }
  for (int f = t; f < 2048; f += 256) {
    int n4 = f & 31, j = f >> 5;
    *(float4*)&Ws[j][n4 * 4] =
        *(const float4*)(inv_w + (size_t)j * 512 + c0 + n4 * 4);
  }
  __syncthreads();
  const int tx = t & 31, ty = t >> 5;
  float acc[4][4];
#pragma unroll
  for (int r = 0; r < 4; ++r)
#pragma unroll
    for (int j = 0; j < 4; ++j) acc[r][j] = 0.f;
#pragma unroll 4
  for (int j = 0; j < 64; ++j) {
    float4 wv = *(const float4*)&Ws[j][tx * 4];
#pragma unroll
    for (int r = 0; r < 4; ++r) {
      float e = Es[ty * 4 + r][j];
      acc[r][0] = fmaf(e, wv.x, acc[r][0]);
      acc[r][1] = fmaf(e, wv.y, acc[r][1]);
      acc[r][2] = fmaf(e, wv.z, acc[r][2]);
      acc[r][3] = fmaf(e, wv.w, acc[r][3]);
    }
  }
  float4 bv = *(const float4*)(inv_b + c0 + tx * 4);
#pragma unroll
  for (int r = 0; r < 4; ++r) {
    float4 o;
    o.x = acc[r][0] + bv.x;
    o.y = acc[r][1] + bv.y;
    o.z = acc[r][2] + bv.z;
    o.w = acc[r][3] + bv.w;
    *(float4*)(out + (size_t)(r0 + ty * 4 + r) * 512 + c0 + tx * 4) = o;
  }
}

// ---------------- launch ----------------
extern "C" void kernel_launch(void* const* d_in, const int* in_sizes, int n_in,
                              void* d_out, int out_size, void* d_ws, size_t ws_size,
                              hipStream_t stream) {
  (void)in_sizes; (void)n_in; (void)out_size; (void)ws_size;
  const float* h_in   = (const float*)d_in[0];
  const int*   mask   = (const int*)d_in[1];
  const float* proj_w = (const float*)d_in[2];
  const float* proj_b = (const float*)d_in[3];
  const float* inv_w  = (const float*)d_in[4];
  const float* inv_b  = (const float*)d_in[5];
  const float* w_in   = (const float*)d_in[6];
  const float* b_in   = (const float*)d_in[7];
  const float* wh     = (const float*)d_in[8];
  const float* bh     = (const float*)d_in[9];
  const float* gam    = (const float*)d_in[10];
  const float* bet    = (const float*)d_in[11];
  const float* w_out  = (const float*)d_in[12];
  const float* b_out  = (const float*)d_in[13];

  float* ws = (float*)d_ws;
  float* XA = ws;                          // 8192*1024 (MLP phase); score scratch aliases this
  float* XB = ws + 8388608;                // 8192*1024
  float* bna = ws + 16777216;              // 1024
  float* bnc = bna + 1024;                 // 1024
  float* h_norm = ws + 16779264;           // 8192*64
  float* e_norm = h_norm + 524288;         // 8192*64
  float* stats  = e_norm + 524288;         // 65536 BN partials (MLP phase)

  // score-phase scratch aliases XA (dead after layer-4 GEMM reads it)
  float* pval    = XA;                     // 8192*4
  int*   pidx    = (int*)(XA + 32768);     // 8192*4
  float* pmax    = XA + 65536;             // 8192*4
  int*   codes   = (int*)(XA + 98304);     // 8192
  float* losspart = XA + 106496;           // 32

  float* out = (float*)d_out;
  float* out_q = out;                      // 4194304
  float* out_code = out + 4194304;         // 8192
  float* out_loss = out + 4202496;         // 1

  // 1. h = h_in @ proj_w + proj_b ; normalize rows
  gemm_bn_relu<64, 64, 32, 4, 4, false><<<dim3(1, 128), 256, 0, stream>>>(
      h_in, proj_w, proj_b, nullptr, nullptr, XB, 8192, 64, 512);
  row_normalize64<<<8192, 64, 0, stream>>>(XB, h_norm);

  // 2. codebook MLP
  embed_bits_in<<<8192, 256, 0, stream>>>(w_in, b_in, XA);
  float* Xcur = XA;
  float* Xnext = XB;
  for (int l = 0; l < 5; ++l) {
    bn_stats_partial<<<dim3(32, 32), 256, 0, stream>>>(Xcur, stats);
    bn_finalize<<<4, 256, 0, stream>>>(stats, gam + l * 1024, bet + l * 1024, bna, bnc);
    if (l < 4) {
      gemm_bn_relu<128, 128, 32, 8, 8, true><<<dim3(8, 64), 256, 0, stream>>>(
          Xcur, wh + (size_t)l * 1024 * 1024, bh + l * 1024, bna, bnc, Xnext,
          8192, 1024, 1024);
      float* tmp = Xcur; Xcur = Xnext; Xnext = tmp;
    } else {
      gemm_bn_relu<64, 64, 32, 4, 4, true><<<dim3(1, 128), 256, 0, stream>>>(
          Xcur, w_out, b_out, bna, bnc, Xnext, 8192, 64, 1024);
    }
  }
  // embed_raw now in Xnext (== XB); normalize rows. XA is now dead -> scratch.
  row_normalize64<<<8192, 64, 0, stream>>>(Xnext, e_norm);

  // 3. gumbel-argmax sampling over 2*h.eN^T, and vq_loss rowmax over eN.eN^T
  score_kernel<true><<<512, 256, 0, stream>>>(h_norm, e_norm, pval, pidx);
  score_kernel<false><<<512, 256, 0, stream>>>(e_norm, e_norm, pmax, nullptr);

  // 4. combine + outputs
  combine_kernel<<<32, 256, 0, stream>>>(pval, pidx, pmax, mask, codes, out_code, losspart);
  loss_final<<<1, 64, 0, stream>>>(losspart, out_loss);
  final_proj<<<dim3(4, 256), 256, 0, stream>>>(e_norm, codes, mask, inv_w, inv_b, out_q);
}

// Round 7
// 1563.992 us; speedup vs baseline: 2.2749x; 2.2749x over previous
//
#include <hip/hip_runtime.h>
#include <hip/hip_bf16.h>
#include <stdint.h>

#define HID 1024

// ---------------- threefry2x32, key = (0,1) (jax.random.key(1)) ----------------
__device__ __forceinline__ uint32_t rotl32(uint32_t x, int r) {
  return (x << r) | (x >> (32 - r));
}

__device__ __forceinline__ uint2 threefry2x32_01(uint32_t x0, uint32_t x1) {
  const uint32_t k0 = 0u, k1 = 1u;
  const uint32_t k2 = k0 ^ k1 ^ 0x1BD11BDAu;
  x0 += k0; x1 += k1;
#define TF_R(r) { x0 += x1; x1 = rotl32(x1, r); x1 ^= x0; }
  TF_R(13) TF_R(15) TF_R(26) TF_R(6)
  x0 += k1; x1 += k2 + 1u;
  TF_R(17) TF_R(29) TF_R(16) TF_R(24)
  x0 += k2; x1 += k0 + 2u;
  TF_R(13) TF_R(15) TF_R(26) TF_R(6)
  x0 += k0; x1 += k1 + 3u;
  TF_R(17) TF_R(29) TF_R(16) TF_R(24)
  x0 += k1; x1 += k2 + 4u;
  TF_R(13) TF_R(15) TF_R(26) TF_R(6)
  x0 += k2; x1 += k0 + 5u;
#undef TF_R
  return make_uint2(x0, x1);
}

// uniform-in-[0,1) bits -> u, jax partitionable mode: ctr=(0, idx), bits = out0^out1
__device__ __forceinline__ float uni_at(uint32_t flat) {
  uint2 y = threefry2x32_01(0u, flat);
  uint32_t b = y.x ^ y.y;
  float f = __uint_as_float((b >> 9) | 0x3f800000u) - 1.0f;
  return fmaxf(f, 1.17549435e-38f);
}

// FAST gumbel: v_log_f32-based, |err| <~ 3e-5 absolute. Hot path (67M calls).
__device__ __forceinline__ float gumbel_fast(uint32_t flat) {
  float u = uni_at(flat);
  float w = -__logf(u);
  return -__logf(w);
}

// EXACT gumbel: correctly-rounded f32 log via double. Called ~2x per row-half.
__device__ __noinline__ float gumbel_exact(uint32_t flat) {
  float u = uni_at(flat);
  float w = -(float)log((double)u);
  float o = (float)log((double)w);
  return -o;
}

__device__ __forceinline__ float f4c(const float4& v, int i) {
  return i == 0 ? v.x : (i == 1 ? v.y : (i == 2 ? v.z : v.w));
}

// rank predicate: (av,ai) strictly above (bv,bi) under first-index-argmax order
__device__ __forceinline__ bool rank_above(float av, int ai, float bv, int bi) {
  return av > bv || (av == bv && ai < bi);
}

// ---------------- generic tiled fp32 GEMM: C = act(A) @ B + bias ----------------
// act(x) = FUSE_BN ? relu(bna[k]*x + bnc[k]) : x   (per-k column params)
template<int BM, int BN_, int BK, int TM, int TN, bool FUSE_BN>
__global__ void __launch_bounds__(256, 4) gemm_bn_relu(
    const float* __restrict__ A, const float* __restrict__ B,
    const float* __restrict__ bias, const float* __restrict__ bna,
    const float* __restrict__ bnc, float* __restrict__ C,
    int M, int N, int K)
{
  __shared__ __align__(16) float As[BK][BM + 4];
  __shared__ __align__(16) float Bs[BK][BN_];
  const int t = threadIdx.x;
  const int n0 = blockIdx.x * BN_;
  const int m0 = blockIdx.y * BM;
  const int tn = t % (BN_ / TN);
  const int tm = t / (BN_ / TN);

  float acc[TM][TN];
#pragma unroll
  for (int i = 0; i < TM; ++i)
#pragma unroll
    for (int j = 0; j < TN; ++j) acc[i][j] = 0.f;

  for (int k0 = 0; k0 < K; k0 += BK) {
    __syncthreads();
    // stage A (BN+ReLU fused), transposed to [k][m]
#pragma unroll
    for (int p = 0; p < BM * BK / 1024; ++p) {
      int f = t + p * 256;
      int kq = f % (BK / 4);
      int m = f / (BK / 4);
      float4 v = *(const float4*)(A + (size_t)(m0 + m) * K + (k0 + kq * 4));
      if constexpr (FUSE_BN) {
        float4 a4 = *(const float4*)(bna + k0 + kq * 4);
        float4 c4 = *(const float4*)(bnc + k0 + kq * 4);
        v.x = fmaxf(fmaf(v.x, a4.x, c4.x), 0.f);
        v.y = fmaxf(fmaf(v.y, a4.y, c4.y), 0.f);
        v.z = fmaxf(fmaf(v.z, a4.z, c4.z), 0.f);
        v.w = fmaxf(fmaf(v.w, a4.w, c4.w), 0.f);
      }
      As[kq * 4 + 0][m] = v.x;
      As[kq * 4 + 1][m] = v.y;
      As[kq * 4 + 2][m] = v.z;
      As[kq * 4 + 3][m] = v.w;
    }
    // stage B
#pragma unroll
    for (int p = 0; p < BK * BN_ / 1024; ++p) {
      int f = t + p * 256;
      int n4 = f % (BN_ / 4);
      int k = f / (BN_ / 4);
      *(float4*)&Bs[k][n4 * 4] =
          *(const float4*)(B + (size_t)(k0 + k) * N + (n0 + n4 * 4));
    }
    __syncthreads();
#pragma unroll 4
    for (int kk = 0; kk < BK; ++kk) {
      float a[TM], b[TN];
      {
        float4 q0 = *(const float4*)&As[kk][tm * 4];
        a[0] = q0.x; a[1] = q0.y; a[2] = q0.z; a[3] = q0.w;
        if constexpr (TM == 8) {
          float4 q1 = *(const float4*)&As[kk][tm * 4 + BM / 2];
          a[4] = q1.x; a[5] = q1.y; a[6] = q1.z; a[7] = q1.w;
        }
        float4 r0 = *(const float4*)&Bs[kk][tn * 4];
        b[0] = r0.x; b[1] = r0.y; b[2] = r0.z; b[3] = r0.w;
        if constexpr (TN == 8) {
          float4 r1 = *(const float4*)&Bs[kk][tn * 4 + BN_ / 2];
          b[4] = r1.x; b[5] = r1.y; b[6] = r1.z; b[7] = r1.w;
        }
      }
#pragma unroll
      for (int i = 0; i < TM; ++i)
#pragma unroll
        for (int j = 0; j < TN; ++j)
          acc[i][j] = fmaf(a[i], b[j], acc[i][j]);
    }
  }
  // epilogue
#pragma unroll
  for (int i = 0; i < TM; ++i) {
    int m = (i < 4) ? (tm * 4 + i) : (tm * 4 + BM / 2 + (i - 4));
#pragma unroll
    for (int jq = 0; jq < TN / 4; ++jq) {
      int n = tn * 4 + jq * (BN_ / 2);
      float4 bv = *(const float4*)(bias + n0 + n);
      float4 o;
      o.x = acc[i][jq * 4 + 0] + bv.x;
      o.y = acc[i][jq * 4 + 1] + bv.y;
      o.z = acc[i][jq * 4 + 2] + bv.z;
      o.w = acc[i][jq * 4 + 3] + bv.w;
      *(float4*)(C + (size_t)(m0 + m) * N + (n0 + n)) = o;
    }
  }
}

// ---------------- codebook bits input layer: X[k][h] = b_in[h] + sum_j bit(k,j)*w_in[j][h]
__global__ void __launch_bounds__(256) embed_bits_in(
    const float* __restrict__ w_in, const float* __restrict__ b_in,
    float* __restrict__ X)
{
  int k = blockIdx.x;
  int c = threadIdx.x * 4;
  float4 acc = *(const float4*)(b_in + c);
#pragma unroll
  for (int j = 0; j < 13; ++j) {
    if (k & (1 << (12 - j))) {
      float4 w = *(const float4*)(w_in + j * HID + c);
      acc.x += w.x; acc.y += w.y; acc.z += w.z; acc.w += w.w;
    }
  }
  *(float4*)(X + (size_t)k * HID + c) = acc;
}

// ---------------- BN stats, stage A: per (rowblock, col) partial sum/sumsq ----------------
__global__ void __launch_bounds__(256) bn_stats_partial(
    const float* __restrict__ X, float* __restrict__ part)
{
  int cb = blockIdx.x, rb = blockIdx.y;
  int t = threadIdx.x;
  int cl = t & 31, rs = t >> 5;
  int c = cb * 32 + cl;
  int r0 = rb * 256 + rs * 32;
  float s = 0.f, sq = 0.f;
  const float* p = X + (size_t)r0 * HID + c;
  for (int i = 0; i < 32; ++i) {
    float v = p[(size_t)i * HID];
    s += v;
    sq = fmaf(v, v, sq);
  }
  __shared__ float rs_[8][32], rq_[8][32];
  rs_[rs][cl] = s;
  rq_[rs][cl] = sq;
  __syncthreads();
  if (t < 32) {
    float S = 0.f, Q = 0.f;
    for (int i = 0; i < 8; ++i) { S += rs_[i][t]; Q += rq_[i][t]; }
    size_t o = ((size_t)rb * HID + cb * 32 + t) * 2;
    part[o] = S;
    part[o + 1] = Q;
  }
}

// ---------------- BN stats, stage B: finalize a[k] = g*rsqrt(var+eps), c[k] = b - m*a ----------------
__global__ void __launch_bounds__(256) bn_finalize(
    const float* __restrict__ part, const float* __restrict__ gamma,
    const float* __restrict__ beta, float* __restrict__ bna,
    float* __restrict__ bnc)
{
  int c = blockIdx.x * 256 + threadIdx.x;
  double S = 0.0, Q = 0.0;
  for (int rb = 0; rb < 32; ++rb) {
    size_t o = ((size_t)rb * HID + c) * 2;
    S += (double)part[o];
    Q += (double)part[o + 1];
  }
  double mean = S / 8192.0;
  double var = Q / 8192.0 - mean * mean;
  float r = (float)(1.0 / sqrt(var + 1e-5));
  float a = gamma[c] * r;
  bna[c] = a;
  bnc[c] = fmaf(-(float)mean, a, beta[c]);
}

// ---------------- row normalize (64-wide rows): out = x / (||x|| + 1e-6) ----------------
__global__ void __launch_bounds__(64) row_normalize64(
    const float* __restrict__ in, float* __restrict__ out)
{
  int r = blockIdx.x, t = threadIdx.x;
  float v = in[(size_t)r * 64 + t];
  float ss = v * v;
  for (int m = 32; m >= 1; m >>= 1) ss += __shfl_xor(ss, m);
  float inv = 1.f / (sqrtf(ss) + 1e-6f);
  out[(size_t)r * 64 + t] = v * inv;
}

// ---------------- score kernel v3: r4 structure + d-chunked staging (25 KB LDS) ----
// grid = 512: (bid>>1) = 32-row group, (bid&1) = k-half (4096 cols), 16 tiles of 256 k.
// Embed tile staged per 16-d chunk as Ed[d][k] (no swizzle needed: inner reads are
// 512B-contiguous + half-wave broadcast). d-accumulation order 0..63 sequential ->
// dots bit-identical to r3/r4 -> same codes.
// GUM=true : z = 2*dot + gumbel; per-thread top-2 + cross-lane top-2 merge +
//            exact-gumbel fallback within 1e-3 margin (code-exact).
// GUM=false: z = dot (diag -> -1), rowmax for vq_loss.
template<bool GUM>
__global__ void __launch_bounds__(256, 2) score_kernel(
    const float* __restrict__ Arows, const float* __restrict__ eN,
    float* __restrict__ pval, int* __restrict__ pidx)
{
  __shared__ __align__(16) float Ed[16][260];  // 16.6 KB
  __shared__ __align__(16) float Hs[32][68];   // 8.7 KB
  const int t = threadIdx.x;
  const int i0 = (blockIdx.x >> 1) * 32;
  const int kh = blockIdx.x & 1;
  for (int f = t; f < 512; f += 256) {
    int lr = f >> 4, dq = (f & 15) << 2;
    *(float4*)&Hs[lr][dq] = *(const float4*)(Arows + (size_t)(i0 + lr) * 64 + dq);
  }
  const int kg = t & 31;  // k lane
  const int rg = t >> 5;  // row group (4 rows)
  float b1[4], b2[4];
  int i1[4], i2[4];
#pragma unroll
  for (int r = 0; r < 4; ++r) { b1[r] = -3.4e38f; b2[r] = -3.4e38f; i1[r] = 0; i2[r] = 0; }

  for (int tile = 0; tile < 16; ++tile) {
    const int kb = kh * 4096 + tile * 256;
    float acc[4][8];
#pragma unroll
    for (int r = 0; r < 4; ++r)
#pragma unroll
      for (int q = 0; q < 8; ++q) acc[r][q] = 0.f;

    for (int dc = 0; dc < 4; ++dc) {
      __syncthreads();
      // stage Ed[d][k] = eN[kb+k][dc*16+d] for d in [0,16)
      {
        const int kk0 = t >> 2, d4 = (t & 3) * 4;
#pragma unroll
        for (int p = 0; p < 4; ++p) {
          int kk = kk0 + p * 64;
          float4 v = *(const float4*)(eN + (size_t)(kb + kk) * 64 + dc * 16 + d4);
          Ed[d4 + 0][kk] = v.x;
          Ed[d4 + 1][kk] = v.y;
          Ed[d4 + 2][kk] = v.z;
          Ed[d4 + 3][kk] = v.w;
        }
      }
      __syncthreads();
#pragma unroll
      for (int dq = 0; dq < 4; ++dq) {
        float4 hq[4];
#pragma unroll
        for (int r = 0; r < 4; ++r)
          hq[r] = *(const float4*)&Hs[rg * 4 + r][dc * 16 + dq * 4];
#pragma unroll
        for (int dd = 0; dd < 4; ++dd) {
          const int d = dq * 4 + dd;
          const float4 ea = *(const float4*)&Ed[d][kg * 4];
          const float4 eb = *(const float4*)&Ed[d][128 + kg * 4];
#pragma unroll
          for (int r = 0; r < 4; ++r) {
            const float hv = f4c(hq[r], dd);
            acc[r][0] = fmaf(hv, ea.x, acc[r][0]);
            acc[r][1] = fmaf(hv, ea.y, acc[r][1]);
            acc[r][2] = fmaf(hv, ea.z, acc[r][2]);
            acc[r][3] = fmaf(hv, ea.w, acc[r][3]);
            acc[r][4] = fmaf(hv, eb.x, acc[r][4]);
            acc[r][5] = fmaf(hv, eb.y, acc[r][5]);
            acc[r][6] = fmaf(hv, eb.z, acc[r][6]);
            acc[r][7] = fmaf(hv, eb.w, acc[r][7]);
          }
        }
      }
    }
    // epilogue: fast gumbel + top-2 update (ascending k within thread)
#pragma unroll
    for (int r = 0; r < 4; ++r) {
      const uint32_t grow = (uint32_t)(i0 + rg * 4 + r);
#pragma unroll
      for (int q = 0; q < 8; ++q) {
        const int kl = (q < 4) ? (kg * 4 + q) : (128 + kg * 4 + (q - 4));
        const int kgl = kb + kl;
        if constexpr (GUM) {
          float g = gumbel_fast((grow << 13) | (uint32_t)kgl);
          float z = fmaf(2.f, acc[r][q], g);
          if (z > b1[r]) {
            b2[r] = b1[r]; i2[r] = i1[r];
            b1[r] = z; i1[r] = kgl;
          } else if (z > b2[r]) {
            b2[r] = z; i2[r] = kgl;
          }
        } else {
          float z = (kgl == (int)grow) ? -1.0f : acc[r][q];
          if (z > b1[r]) b1[r] = z;
        }
      }
    }
  }
  // cross-lane (32 lanes share the same 4 rows) reduce
#pragma unroll
  for (int r = 0; r < 4; ++r) {
    if constexpr (GUM) {
      float v1 = b1[r], v2 = b2[r];
      int j1 = i1[r], j2 = i2[r];
      for (int m = 16; m >= 1; m >>= 1) {
        float o1 = __shfl_xor(v1, m), o2 = __shfl_xor(v2, m);
        int p1 = __shfl_xor(j1, m), p2 = __shfl_xor(j2, m);
        if (rank_above(o1, p1, v1, j1)) {
          float nv2; int nj2;
          if (rank_above(v1, j1, o2, p2)) { nv2 = v1; nj2 = j1; }
          else { nv2 = o2; nj2 = p2; }
          v1 = o1; j1 = p1; v2 = nv2; j2 = nj2;
        } else {
          if (rank_above(o1, p1, v2, j2)) { v2 = o1; j2 = p1; }
        }
      }
      if ((t & 31) == 0) {
        const uint32_t grow = (uint32_t)(i0 + rg * 4 + r);
        float g1f = gumbel_fast((grow << 13) | (uint32_t)j1);
        float g1e = gumbel_exact((grow << 13) | (uint32_t)j1);
        float z1 = v1 - g1f + g1e;
        int win = j1;
        if (v1 - v2 <= 1e-3f) {
          float g2f = gumbel_fast((grow << 13) | (uint32_t)j2);
          float g2e = gumbel_exact((grow << 13) | (uint32_t)j2);
          float z2 = v2 - g2f + g2e;
          if (rank_above(z2, j2, z1, win)) { z1 = z2; win = j2; }
        }
        pval[(size_t)grow * 2 + kh] = z1;
        pidx[(size_t)grow * 2 + kh] = win;
      }
    } else {
      float bv = b1[r];
      for (int m = 16; m >= 1; m >>= 1) {
        float ov = __shfl_xor(bv, m);
        if (ov > bv) bv = ov;
      }
      if ((t & 31) == 0) {
        int grow = i0 + rg * 4 + r;
        pval[(size_t)grow * 2 + kh] = bv;
      }
    }
  }
}

// ---------------- combine: codes, masked code output, per-block loss partial ----------------
__global__ void __launch_bounds__(256) combine_kernel(
    const float* __restrict__ pval, const int* __restrict__ pidx,
    const float* __restrict__ pmax, const int* __restrict__ mask,
    int* __restrict__ codes, float* __restrict__ out_code,
    float* __restrict__ losspart)
{
  int r = blockIdx.x * 256 + threadIdx.x;
  float v0 = pval[(size_t)r * 2], v1 = pval[(size_t)r * 2 + 1];
  int j0 = pidx[(size_t)r * 2], j1 = pidx[(size_t)r * 2 + 1];
  int code = rank_above(v1, j1, v0, j0) ? j1 : j0;
  codes[r] = code;
  out_code[r] = (mask[r] != 0) ? (float)code : 0.f;
  float m = fmaxf(pmax[(size_t)r * 2], pmax[(size_t)r * 2 + 1]);
  __shared__ float red[256];
  red[threadIdx.x] = m;
  __syncthreads();
  for (int s = 128; s >= 1; s >>= 1) {
    if (threadIdx.x < s) red[threadIdx.x] += red[threadIdx.x + s];
    __syncthreads();
  }
  if (threadIdx.x == 0) losspart[blockIdx.x] = red[0];
}

__global__ void __launch_bounds__(64) loss_final(
    const float* __restrict__ losspart, float* __restrict__ out)
{
  float s = (threadIdx.x < 32) ? losspart[threadIdx.x] : 0.f;
  for (int m = 32; m >= 1; m >>= 1) s += __shfl_xor(s, m);
  if (threadIdx.x == 0) out[0] = s * (1.0f / 8192.0f);
}

// ---------------- final projection: out = (mask ? eN[code] : 0) @ inv_w + inv_b ----------------
__global__ void __launch_bounds__(256, 2) final_proj(
    const float* __restrict__ eN, const int* __restrict__ codes,
    const int* __restrict__ mask, const float* __restrict__ inv_w,
    const float* __restrict__ inv_b, float* __restrict__ out)
{
  __shared__ __align__(16) float Ws[64][128];
  __shared__ __align__(16) float Es[32][64];
  const int t = threadIdx.x;
  const int c0 = blockIdx.x * 128;
  const int r0 = blockIdx.y * 32;
  for (int f = t; f < 512; f += 256) {
    int lr = f >> 4, dq = (f & 15) << 2;
    int grow = r0 + lr;
    float4 v = make_float4(0.f, 0.f, 0.f, 0.f);
    if (mask[grow] != 0)
      v = *(const float4*)(eN + (size_t)codes[grow] * 64 + dq);
    *(float4*)&Es[lr][dq] = v;
  }
  for (int f = t; f < 2048; f += 256) {
    int n4 = f & 31, j = f >> 5;
    *(float4*)&Ws[j][n4 * 4] =
        *(const float4*)(inv_w + (size_t)j * 512 + c0 + n4 * 4);
  }
  __syncthreads();
  const int tx = t & 31, ty = t >> 5;
  float acc[4][4];
#pragma unroll
  for (int r = 0; r < 4; ++r)
#pragma unroll
    for (int j = 0; j < 4; ++j) acc[r][j] = 0.f;
#pragma unroll 4
  for (int j = 0; j < 64; ++j) {
    float4 wv = *(const float4*)&Ws[j][tx * 4];
#pragma unroll
    for (int r = 0; r < 4; ++r) {
      float e = Es[ty * 4 + r][j];
      acc[r][0] = fmaf(e, wv.x, acc[r][0]);
      acc[r][1] = fmaf(e, wv.y, acc[r][1]);
      acc[r][2] = fmaf(e, wv.z, acc[r][2]);
      acc[r][3] = fmaf(e, wv.w, acc[r][3]);
    }
  }
  float4 bv = *(const float4*)(inv_b + c0 + tx * 4);
#pragma unroll
  for (int r = 0; r < 4; ++r) {
    float4 o;
    o.x = acc[r][0] + bv.x;
    o.y = acc[r][1] + bv.y;
    o.z = acc[r][2] + bv.z;
    o.w = acc[r][3] + bv.w;
    *(float4*)(out + (size_t)(r0 + ty * 4 + r) * 512 + c0 + tx * 4) = o;
  }
}

// ---------------- launch ----------------
extern "C" void kernel_launch(void* const* d_in, const int* in_sizes, int n_in,
                              void* d_out, int out_size, void* d_ws, size_t ws_size,
                              hipStream_t stream) {
  (void)in_sizes; (void)n_in; (void)out_size; (void)ws_size;
  const float* h_in   = (const float*)d_in[0];
  const int*   mask   = (const int*)d_in[1];
  const float* proj_w = (const float*)d_in[2];
  const float* proj_b = (const float*)d_in[3];
  const float* inv_w  = (const float*)d_in[4];
  const float* inv_b  = (const float*)d_in[5];
  const float* w_in   = (const float*)d_in[6];
  const float* b_in   = (const float*)d_in[7];
  const float* wh     = (const float*)d_in[8];
  const float* bh     = (const float*)d_in[9];
  const float* gam    = (const float*)d_in[10];
  const float* bet    = (const float*)d_in[11];
  const float* w_out  = (const float*)d_in[12];
  const float* b_out  = (const float*)d_in[13];

  float* ws = (float*)d_ws;
  float* XA = ws;                          // 8192*1024 (MLP phase); score scratch aliases this
  float* XB = ws + 8388608;                // 8192*1024
  float* bna = ws + 16777216;              // 1024
  float* bnc = bna + 1024;                 // 1024
  float* h_norm = ws + 16779264;           // 8192*64
  float* e_norm = h_norm + 524288;         // 8192*64
  float* stats  = e_norm + 524288;         // 65536 BN partials (MLP phase)

  // score-phase scratch aliases XA (dead after layer-4 GEMM reads it)
  float* pval    = XA;                     // 8192*2
  int*   pidx    = (int*)(XA + 16384);     // 8192*2
  float* pmax    = XA + 32768;             // 8192*2
  int*   codes   = (int*)(XA + 49152);     // 8192
  float* losspart = XA + 57344;            // 32

  float* out = (float*)d_out;
  float* out_q = out;                      // 4194304
  float* out_code = out + 4194304;         // 8192
  float* out_loss = out + 4202496;         // 1

  // 1. h = h_in @ proj_w + proj_b ; normalize rows
  gemm_bn_relu<64, 64, 32, 4, 4, false><<<dim3(1, 128), 256, 0, stream>>>(
      h_in, proj_w, proj_b, nullptr, nullptr, XB, 8192, 64, 512);
  row_normalize64<<<8192, 64, 0, stream>>>(XB, h_norm);

  // 2. codebook MLP
  embed_bits_in<<<8192, 256, 0, stream>>>(w_in, b_in, XA);
  float* Xcur = XA;
  float* Xnext = XB;
  for (int l = 0; l < 5; ++l) {
    bn_stats_partial<<<dim3(32, 32), 256, 0, stream>>>(Xcur, stats);
    bn_finalize<<<4, 256, 0, stream>>>(stats, gam + l * 1024, bet + l * 1024, bna, bnc);
    if (l < 4) {
      gemm_bn_relu<128, 128, 32, 8, 8, true><<<dim3(8, 64), 256, 0, stream>>>(
          Xcur, wh + (size_t)l * 1024 * 1024, bh + l * 1024, bna, bnc, Xnext,
          8192, 1024, 1024);
      float* tmp = Xcur; Xcur = Xnext; Xnext = tmp;
    } else {
      gemm_bn_relu<64, 64, 32, 4, 4, true><<<dim3(1, 128), 256, 0, stream>>>(
          Xcur, w_out, b_out, bna, bnc, Xnext, 8192, 64, 1024);
    }
  }
  // embed_raw now in Xnext (== XB); normalize rows. XA is now dead -> scratch.
  row_normalize64<<<8192, 64, 0, stream>>>(Xnext, e_norm);

  // 3. gumbel-argmax sampling over 2*h.eN^T, and vq_loss rowmax over eN.eN^T
  score_kernel<true><<<512, 256, 0, stream>>>(h_norm, e_norm, pval, pidx);
  score_kernel<false><<<512, 256, 0, stream>>>(e_norm, e_norm, pmax, nullptr);

  // 4. combine + outputs
  combine_kernel<<<32, 256, 0, stream>>>(pval, pidx, pmax, mask, codes, out_code, losspart);
  loss_final<<<1, 64, 0, stream>>>(losspart, out_loss);
  final_proj<<<dim3(4, 256), 256, 0, stream>>>(e_norm, codes, mask, inv_w, inv_b, out_q);
}